// Round 5
// baseline (109.420 us; speedup 1.0000x reference)
//
#include <hip/hip_runtime.h>
#include <math.h>

#define NBLK 2048
#define NT 256
// NBLK * NT * 2 samples/thread = 1048576 = B exactly.
#define CNT_OFF (NBLK * 8)        // after float2 partials[NBLK]
#define TBL_OFF (CNT_OFF + 64)    // 48-float coef table

__device__ __forceinline__ float zsel(float s, float n) {
    // (sigmoid(s) > n)  <=>  (1-n) > n*exp(-s)
    float e = __expf(-s);
    return (1.0f - n > n * e) ? 1.0f : 0.0f;
}
__device__ __forceinline__ float sp_f(float l) {  // softplus
    return fmaxf(l, 0.0f) + __logf(1.0f + __expf(-fabsf(l)));
}

// ---------------- kernel A: build bilinear coefficient tables ----------------
// tbl[(pair*4+t)*2+e]: P0=(sig40,sig41)[z3] P1=(l30,l31)[z4] P2=(SP30,SP31)[z4]
// P3=(l10,l11)[z2] P4=(SP10,SP11)[z2] P5=(muy2[z3], muy1[z1])
__global__ __launch_bounds__(64) void make_tables(
    const float* __restrict__ i3w1, const float* __restrict__ i3b1,
    const float* __restrict__ i3w2, const float* __restrict__ i3b2,
    const float* __restrict__ g1w1, const float* __restrict__ g1b1,
    const float* __restrict__ g1w2, const float* __restrict__ g1b2,
    const float* __restrict__ g2w1, const float* __restrict__ g2b1,
    const float* __restrict__ g2w2, const float* __restrict__ g2b2,
    const float* __restrict__ g4w1, const float* __restrict__ g4b1,
    const float* __restrict__ g4w2, const float* __restrict__ g4b2,
    const float* __restrict__ g5w1, const float* __restrict__ g5b1,
    const float* __restrict__ g5w2, const float* __restrict__ g5b2,
    float* __restrict__ tbl)
{
    __shared__ float lds_eval[5][4][2];
    const int tid = threadIdx.x;
    if (tid < 20) {
        const int m = tid >> 2, c = tid & 3;
        const float z0 = (float)(c & 1), z1f = (float)(c >> 1);
        const float *w1, *bb1, *w2, *bb2; int dout;
        switch (m) {
            case 0:  w1 = i3w1; bb1 = i3b1; w2 = i3w2; bb2 = i3b2; dout = 2; break;
            case 1:  w1 = g1w1; bb1 = g1b1; w2 = g1w2; bb2 = g1b2; dout = 2; break;
            case 2:  w1 = g2w1; bb1 = g2b1; w2 = g2w2; bb2 = g2b2; dout = 1; break;
            case 3:  w1 = g4w1; bb1 = g4b1; w2 = g4w2; bb2 = g4b2; dout = 2; break;
            default: w1 = g5w1; bb1 = g5b1; w2 = g5w2; bb2 = g5b2; dout = 1; break;
        }
        float o0 = bb2[0];
        float o1 = (dout == 2) ? bb2[1] : 0.0f;
        #pragma unroll
        for (int j = 0; j < 8; ++j) {
            float h = fmaxf(bb1[j] + z0 * w1[j] + z1f * w1[8 + j], 0.0f);
            o0 += h * w2[j * dout];
            if (dout == 2) o1 += h * w2[j * 2 + 1];
        }
        lds_eval[m][c][0] = o0;
        lds_eval[m][c][1] = o1;
    }
    __syncthreads();
    if (tid < 12) {
        const int pair = tid >> 1, elem = tid & 1;
        int m, k, tf;
        switch (tid) {
            case 0:  m = 0; k = 0; tf = 1; break;  // sig40
            case 1:  m = 0; k = 1; tf = 1; break;  // sig41
            case 2:  m = 1; k = 0; tf = 0; break;  // l30
            case 3:  m = 1; k = 1; tf = 0; break;  // l31
            case 4:  m = 1; k = 0; tf = 2; break;  // SP30
            case 5:  m = 1; k = 1; tf = 2; break;  // SP31
            case 6:  m = 3; k = 0; tf = 0; break;  // l10
            case 7:  m = 3; k = 1; tf = 0; break;  // l11
            case 8:  m = 3; k = 0; tf = 2; break;  // SP10
            case 9:  m = 3; k = 1; tf = 2; break;  // SP11
            case 10: m = 2; k = 0; tf = 0; break;  // muy2
            default: m = 4; k = 0; tf = 0; break;  // muy1
        }
        float f[4];
        #pragma unroll
        for (int c = 0; c < 4; ++c) {
            float x = lds_eval[m][c][k];
            if (tf == 1)      x = 1.0f / (1.0f + expf(-x));
            else if (tf == 2) x = fmaxf(x, 0.0f) + log1pf(expf(-fabsf(x)));
            f[c] = x;
        }
        tbl[(pair * 4 + 0) * 2 + elem] = f[0];
        tbl[(pair * 4 + 1) * 2 + elem] = f[1] - f[0];
        tbl[(pair * 4 + 2) * 2 + elem] = f[2] - f[0];
        tbl[(pair * 4 + 3) * 2 + elem] = f[3] - f[1] - f[2] + f[0];
    }
}

// Per-sample body: scalar-indexed weight access (uniform -> SGPR, do NOT
// pointer-cast the weight arrays; that demotes them to per-lane VMEM, R2 bug).
__device__ __forceinline__ void sample_body(
    float Y1, float Y2,
    float N10, float N11, float N20, float N21,
    float N30, float N31, float N40, float N41,
    const float* __restrict__ i0w1, const float* __restrict__ i0b1,
    const float* __restrict__ i0w2, const float* __restrict__ i0b2,
    const float* __restrict__ i1w1, const float* __restrict__ i1b1,
    const float* __restrict__ i1w2, const float* __restrict__ i1b2,
    const float* __restrict__ i2w1, const float* __restrict__ i2b1,
    const float* __restrict__ i2w2, const float* __restrict__ i2b2,
    const float* __restrict__ g3w1, const float* __restrict__ g3b1,
    const float* __restrict__ g3w2, const float* __restrict__ g3b2,
    float L40, float L41, const float* __restrict__ tbl,
    float& lz, float& ly)
{
    // inf0([y1,y2]) -> z1
    float a0 = i0b2[0], a1 = i0b2[1];
    #pragma unroll
    for (int j = 0; j < 8; ++j) {
        float h = fmaxf(i0b1[j] + Y1 * i0w1[j] + Y2 * i0w1[8 + j], 0.0f);
        a0 += h * i0w2[2 * j]; a1 += h * i0w2[2 * j + 1];
    }
    const float z10 = zsel(a0, N10);
    const float z11 = zsel(a1, N11);

    // inf1([y2,z1]) -> z2
    float b0 = i1b2[0], b1v = i1b2[1];
    #pragma unroll
    for (int j = 0; j < 8; ++j) {
        float h = fmaxf(i1b1[j] + Y2 * i1w1[j] + z10 * i1w1[8 + j]
                        + z11 * i1w1[16 + j], 0.0f);
        b0 += h * i1w2[2 * j]; b1v += h * i1w2[2 * j + 1];
    }
    const float z20 = zsel(b0, N20);
    const float z21 = zsel(b1v, N21);

    // inf2(y2) -> z3
    float c0 = i2b2[0], c1 = i2b2[1];
    #pragma unroll
    for (int j = 0; j < 8; ++j) {
        float h = fmaxf(i2b1[j] + Y2 * i2w1[j], 0.0f);
        c0 += h * i2w2[2 * j]; c1 += h * i2w2[2 * j + 1];
    }
    const float z30 = zsel(c0, N30);
    const float z31 = zsel(c1, N31);

    // z4 via tabulated sigmoid over z3 corners
    const float p3 = z30 * z31;
    const float sg0 = tbl[0] + tbl[2] * z30 + tbl[4] * z31 + tbl[6] * p3;
    const float sg1 = tbl[1] + tbl[3] * z30 + tbl[5] * z31 + tbl[7] * p3;
    const float z40 = (sg0 > N40) ? 1.0f : 0.0f;
    const float z41 = (sg1 > N41) ? 1.0f : 0.0f;
    const float p4 = z40 * z41;

    // g3(y2) -> l2 (continuous-input MLP)
    float l20 = g3b2[0], l21 = g3b2[1];
    #pragma unroll
    for (int j = 0; j < 8; ++j) {
        float h = fmaxf(g3b1[j] + Y2 * g3w1[j], 0.0f);
        l20 += h * g3w2[2 * j]; l21 += h * g3w2[2 * j + 1];
    }

    // table losses
    const float l3a  = tbl[8]  + tbl[10] * z40 + tbl[12] * z41 + tbl[14] * p4;
    const float l3b  = tbl[9]  + tbl[11] * z40 + tbl[13] * z41 + tbl[15] * p4;
    const float SP3a = tbl[16] + tbl[18] * z40 + tbl[20] * z41 + tbl[22] * p4;
    const float SP3b = tbl[17] + tbl[19] * z40 + tbl[21] * z41 + tbl[23] * p4;
    const float p2 = z20 * z21;
    const float l1a  = tbl[24] + tbl[26] * z20 + tbl[28] * z21 + tbl[30] * p2;
    const float l1b  = tbl[25] + tbl[27] * z20 + tbl[29] * z21 + tbl[31] * p2;
    const float SP1a = tbl[32] + tbl[34] * z20 + tbl[36] * z21 + tbl[38] * p2;
    const float SP1b = tbl[33] + tbl[35] * z20 + tbl[37] * z21 + tbl[39] * p2;
    const float mu2  = tbl[40] + tbl[42] * z30 + tbl[44] * z31 + tbl[46] * p3;
    const float p1 = z10 * z11;
    const float mu1  = tbl[41] + tbl[43] * z10 + tbl[45] * z11 + tbl[47] * p1;

    lz += (SP1a - l1a * z10) + (SP1b - l1b * z11)
        + (sp_f(l20) - l20 * z20) + (sp_f(l21) - l21 * z21)
        + (SP3a - l3a * z30) + (SP3b - l3b * z31)
        - (L40 * z40 + L41 * z41);
    const float d1 = Y1 - mu1, d2 = Y2 - mu2;
    ly += d1 * d1 + d2 * d2;  // *2 applied at the end
}

// ---------------- kernel B: main, 2 samples/thread, fused final reduce ----------------
__global__ __launch_bounds__(NT) void wake_main(
    const float* __restrict__ y1, const float* __restrict__ y2,
    const float* __restrict__ n1, const float* __restrict__ n2,
    const float* __restrict__ n3, const float* __restrict__ n4,
    const float* __restrict__ i0w1, const float* __restrict__ i0b1,
    const float* __restrict__ i0w2, const float* __restrict__ i0b2,
    const float* __restrict__ i1w1, const float* __restrict__ i1b1,
    const float* __restrict__ i1w2, const float* __restrict__ i1b2,
    const float* __restrict__ i2w1, const float* __restrict__ i2b1,
    const float* __restrict__ i2w2, const float* __restrict__ i2b2,
    const float* __restrict__ g3w1, const float* __restrict__ g3b1,
    const float* __restrict__ g3w2, const float* __restrict__ g3b2,
    const float* __restrict__ g0w,
    const float* __restrict__ tbl,
    float2* __restrict__ partials, unsigned* __restrict__ cnt,
    float* __restrict__ out)
{
    const int tid = threadIdx.x;
    const int g = blockIdx.x * NT + tid;

    // per-thread data: 80 B, all wide loads, issued up front
    const float2 Y1v = reinterpret_cast<const float2*>(y1)[g];
    const float2 Y2v = reinterpret_cast<const float2*>(y2)[g];
    const float4 N1v = reinterpret_cast<const float4*>(n1)[g];
    const float4 N2v = reinterpret_cast<const float4*>(n2)[g];
    const float4 N3v = reinterpret_cast<const float4*>(n3)[g];
    const float4 N4v = reinterpret_cast<const float4*>(n4)[g];

    const float L40 = g0w[0], L41 = g0w[1];

    float lz = 0.0f, ly = 0.0f;
    sample_body(Y1v.x, Y2v.x, N1v.x, N1v.y, N2v.x, N2v.y,
                N3v.x, N3v.y, N4v.x, N4v.y,
                i0w1, i0b1, i0w2, i0b2, i1w1, i1b1, i1w2, i1b2,
                i2w1, i2b1, i2w2, i2b2, g3w1, g3b1, g3w2, g3b2,
                L40, L41, tbl, lz, ly);
    sample_body(Y1v.y, Y2v.y, N1v.z, N1v.w, N2v.z, N2v.w,
                N3v.z, N3v.w, N4v.z, N4v.w,
                i0w1, i0b1, i0w2, i0b2, i1w1, i1b1, i1w2, i1b2,
                i2w1, i2b1, i2w2, i2b2, g3w1, g3b1, g3w2, g3b2,
                L40, L41, tbl, lz, ly);

    // block reduction -> one float2 partial per block
    #pragma unroll
    for (int off = 32; off > 0; off >>= 1) {
        lz += __shfl_down(lz, off);
        ly += __shfl_down(ly, off);
    }
    __shared__ float2 wsum[NT / 64];
    __shared__ int sflag;
    const int lane = tid & 63, wid = tid >> 6;
    if (lane == 0) wsum[wid] = make_float2(lz, ly);
    __syncthreads();
    if (tid == 0) {
        float a = 0.0f, b = 0.0f;
        #pragma unroll
        for (int w = 0; w < NT / 64; ++w) { a += wsum[w].x; b += wsum[w].y; }
        union { float2 f; unsigned long long u; } pk;
        pk.f = make_float2(a, b);
        __hip_atomic_store((unsigned long long*)&partials[blockIdx.x], pk.u,
                           __ATOMIC_RELEASE, __HIP_MEMORY_SCOPE_AGENT);
        unsigned v = __hip_atomic_fetch_add(cnt, 1u, __ATOMIC_ACQ_REL,
                                            __HIP_MEMORY_SCOPE_AGENT);
        sflag = (v == NBLK - 1);
    }
    __syncthreads();
    // last block folds all partials in fixed order -> deterministic
    if (sflag) {
        float a = 0.0f, b = 0.0f;
        #pragma unroll
        for (int i = 0; i < NBLK / NT; ++i) {
            union { float2 f; unsigned long long u; } q;
            q.u = __hip_atomic_load((const unsigned long long*)&partials[tid + i * NT],
                                    __ATOMIC_ACQUIRE, __HIP_MEMORY_SCOPE_AGENT);
            a += q.f.x; b += q.f.y;
        }
        #pragma unroll
        for (int off = 32; off > 0; off >>= 1) {
            a += __shfl_down(a, off);
            b += __shfl_down(b, off);
        }
        if (lane == 0) wsum[wid] = make_float2(a, b);
        __syncthreads();
        if (tid == 0) {
            float sa = 0.0f, sb = 0.0f;
            #pragma unroll
            for (int w = 0; w < NT / 64; ++w) { sa += wsum[w].x; sb += wsum[w].y; }
            const float c4 = fmaxf(L40, 0.0f) + log1pf(expf(-fabsf(L40)))
                           + fmaxf(L41, 0.0f) + log1pf(expf(-fabsf(L41)));
            const float inv = 1.0f / 1048576.0f;
            const float loss_z = sa * inv + c4;
            const float loss_y = 2.0f * sb * inv + 0.4515827052894548f;
            out[0] = loss_z + loss_y;
            out[1] = loss_z;
            out[2] = loss_y;
        }
    }
}

extern "C" void kernel_launch(void* const* d_in, const int* in_sizes, int n_in,
                              void* d_out, int out_size, void* d_ws, size_t ws_size,
                              hipStream_t stream) {
    const float* p[43];
    for (int i = 0; i < 43; ++i) p[i] = (const float*)d_in[i];
    float2* partials = (float2*)d_ws;
    unsigned* cnt = (unsigned*)((char*)d_ws + CNT_OFF);
    float* tbl = (float*)((char*)d_ws + TBL_OFF);

    hipMemsetAsync(cnt, 0, sizeof(unsigned), stream);
    // binary-input MLP weights: inf3=18..21, g1=22..25, g2=26..29, g4=34..37, g5=38..41
    make_tables<<<1, 64, 0, stream>>>(
        p[18], p[19], p[20], p[21],
        p[22], p[23], p[24], p[25],
        p[26], p[27], p[28], p[29],
        p[34], p[35], p[36], p[37],
        p[38], p[39], p[40], p[41],
        tbl);
    wake_main<<<NBLK, NT, 0, stream>>>(
        p[0], p[1], p[2], p[3], p[4], p[5],
        p[6], p[7], p[8], p[9],
        p[10], p[11], p[12], p[13],
        p[14], p[15], p[16], p[17],
        p[30], p[31], p[32], p[33],
        p[42], tbl, partials, cnt, (float*)d_out);
}

// Round 6
// 31.153 us; speedup vs baseline: 3.5124x; 3.5124x over previous
//
#include <hip/hip_runtime.h>
#include <math.h>

#define NBLK 2048
#define NT 256
// NBLK * NT * 2 samples/thread = 1048576 = B exactly.
#define TBL_OFF (NBLK * 8)  // coef table after float2 partials[NBLK]

__device__ __forceinline__ float zsel(float s, float n) {
    // (sigmoid(s) > n)  <=>  (1-n) > n*exp(-s)
    float e = __expf(-s);
    return (1.0f - n > n * e) ? 1.0f : 0.0f;
}
__device__ __forceinline__ float sp_f(float l) {  // softplus
    return fmaxf(l, 0.0f) + __logf(1.0f + __expf(-fabsf(l)));
}

// ---------------- kernel A: build bilinear coefficient tables ----------------
// tbl[(pair*4+t)*2+e]: P0=(sig40,sig41)[z3] P1=(l30,l31)[z4] P2=(SP30,SP31)[z4]
// P3=(l10,l11)[z2] P4=(SP10,SP11)[z2] P5=(muy2[z3], muy1[z1])
__global__ __launch_bounds__(64) void make_tables(
    const float* __restrict__ i3w1, const float* __restrict__ i3b1,
    const float* __restrict__ i3w2, const float* __restrict__ i3b2,
    const float* __restrict__ g1w1, const float* __restrict__ g1b1,
    const float* __restrict__ g1w2, const float* __restrict__ g1b2,
    const float* __restrict__ g2w1, const float* __restrict__ g2b1,
    const float* __restrict__ g2w2, const float* __restrict__ g2b2,
    const float* __restrict__ g4w1, const float* __restrict__ g4b1,
    const float* __restrict__ g4w2, const float* __restrict__ g4b2,
    const float* __restrict__ g5w1, const float* __restrict__ g5b1,
    const float* __restrict__ g5w2, const float* __restrict__ g5b2,
    float* __restrict__ tbl)
{
    __shared__ float lds_eval[5][4][2];
    const int tid = threadIdx.x;
    if (tid < 20) {
        const int m = tid >> 2, c = tid & 3;
        const float z0 = (float)(c & 1), z1f = (float)(c >> 1);
        const float *w1, *bb1, *w2, *bb2; int dout;
        switch (m) {
            case 0:  w1 = i3w1; bb1 = i3b1; w2 = i3w2; bb2 = i3b2; dout = 2; break;
            case 1:  w1 = g1w1; bb1 = g1b1; w2 = g1w2; bb2 = g1b2; dout = 2; break;
            case 2:  w1 = g2w1; bb1 = g2b1; w2 = g2w2; bb2 = g2b2; dout = 1; break;
            case 3:  w1 = g4w1; bb1 = g4b1; w2 = g4w2; bb2 = g4b2; dout = 2; break;
            default: w1 = g5w1; bb1 = g5b1; w2 = g5w2; bb2 = g5b2; dout = 1; break;
        }
        float o0 = bb2[0];
        float o1 = (dout == 2) ? bb2[1] : 0.0f;
        #pragma unroll
        for (int j = 0; j < 8; ++j) {
            float h = fmaxf(bb1[j] + z0 * w1[j] + z1f * w1[8 + j], 0.0f);
            o0 += h * w2[j * dout];
            if (dout == 2) o1 += h * w2[j * 2 + 1];
        }
        lds_eval[m][c][0] = o0;
        lds_eval[m][c][1] = o1;
    }
    __syncthreads();
    if (tid < 12) {
        const int pair = tid >> 1, elem = tid & 1;
        int m, k, tf;
        switch (tid) {
            case 0:  m = 0; k = 0; tf = 1; break;  // sig40
            case 1:  m = 0; k = 1; tf = 1; break;  // sig41
            case 2:  m = 1; k = 0; tf = 0; break;  // l30
            case 3:  m = 1; k = 1; tf = 0; break;  // l31
            case 4:  m = 1; k = 0; tf = 2; break;  // SP30
            case 5:  m = 1; k = 1; tf = 2; break;  // SP31
            case 6:  m = 3; k = 0; tf = 0; break;  // l10
            case 7:  m = 3; k = 1; tf = 0; break;  // l11
            case 8:  m = 3; k = 0; tf = 2; break;  // SP10
            case 9:  m = 3; k = 1; tf = 2; break;  // SP11
            case 10: m = 2; k = 0; tf = 0; break;  // muy2
            default: m = 4; k = 0; tf = 0; break;  // muy1
        }
        float f[4];
        #pragma unroll
        for (int c = 0; c < 4; ++c) {
            float x = lds_eval[m][c][k];
            if (tf == 1)      x = 1.0f / (1.0f + expf(-x));
            else if (tf == 2) x = fmaxf(x, 0.0f) + log1pf(expf(-fabsf(x)));
            f[c] = x;
        }
        tbl[(pair * 4 + 0) * 2 + elem] = f[0];
        tbl[(pair * 4 + 1) * 2 + elem] = f[1] - f[0];
        tbl[(pair * 4 + 2) * 2 + elem] = f[2] - f[0];
        tbl[(pair * 4 + 3) * 2 + elem] = f[3] - f[1] - f[2] + f[0];
    }
}

// Per-sample body: scalar-indexed weight access (uniform -> SGPR; never
// pointer-cast the weight arrays to vector types — that demotes them to
// per-lane VMEM loads inside the loop, the R2 bug).
__device__ __forceinline__ void sample_body(
    float Y1, float Y2,
    float N10, float N11, float N20, float N21,
    float N30, float N31, float N40, float N41,
    const float* __restrict__ i0w1, const float* __restrict__ i0b1,
    const float* __restrict__ i0w2, const float* __restrict__ i0b2,
    const float* __restrict__ i1w1, const float* __restrict__ i1b1,
    const float* __restrict__ i1w2, const float* __restrict__ i1b2,
    const float* __restrict__ i2w1, const float* __restrict__ i2b1,
    const float* __restrict__ i2w2, const float* __restrict__ i2b2,
    const float* __restrict__ g3w1, const float* __restrict__ g3b1,
    const float* __restrict__ g3w2, const float* __restrict__ g3b2,
    float L40, float L41, const float* __restrict__ tbl,
    float& lz, float& ly)
{
    // inf0([y1,y2]) -> z1
    float a0 = i0b2[0], a1 = i0b2[1];
    #pragma unroll
    for (int j = 0; j < 8; ++j) {
        float h = fmaxf(i0b1[j] + Y1 * i0w1[j] + Y2 * i0w1[8 + j], 0.0f);
        a0 += h * i0w2[2 * j]; a1 += h * i0w2[2 * j + 1];
    }
    const float z10 = zsel(a0, N10);
    const float z11 = zsel(a1, N11);

    // inf1([y2,z1]) -> z2
    float b0 = i1b2[0], b1v = i1b2[1];
    #pragma unroll
    for (int j = 0; j < 8; ++j) {
        float h = fmaxf(i1b1[j] + Y2 * i1w1[j] + z10 * i1w1[8 + j]
                        + z11 * i1w1[16 + j], 0.0f);
        b0 += h * i1w2[2 * j]; b1v += h * i1w2[2 * j + 1];
    }
    const float z20 = zsel(b0, N20);
    const float z21 = zsel(b1v, N21);

    // inf2(y2) -> z3
    float c0 = i2b2[0], c1 = i2b2[1];
    #pragma unroll
    for (int j = 0; j < 8; ++j) {
        float h = fmaxf(i2b1[j] + Y2 * i2w1[j], 0.0f);
        c0 += h * i2w2[2 * j]; c1 += h * i2w2[2 * j + 1];
    }
    const float z30 = zsel(c0, N30);
    const float z31 = zsel(c1, N31);

    // z4 via tabulated sigmoid over z3 corners
    const float p3 = z30 * z31;
    const float sg0 = tbl[0] + tbl[2] * z30 + tbl[4] * z31 + tbl[6] * p3;
    const float sg1 = tbl[1] + tbl[3] * z30 + tbl[5] * z31 + tbl[7] * p3;
    const float z40 = (sg0 > N40) ? 1.0f : 0.0f;
    const float z41 = (sg1 > N41) ? 1.0f : 0.0f;
    const float p4 = z40 * z41;

    // g3(y2) -> l2 (continuous-input MLP)
    float l20 = g3b2[0], l21 = g3b2[1];
    #pragma unroll
    for (int j = 0; j < 8; ++j) {
        float h = fmaxf(g3b1[j] + Y2 * g3w1[j], 0.0f);
        l20 += h * g3w2[2 * j]; l21 += h * g3w2[2 * j + 1];
    }

    // table losses
    const float l3a  = tbl[8]  + tbl[10] * z40 + tbl[12] * z41 + tbl[14] * p4;
    const float l3b  = tbl[9]  + tbl[11] * z40 + tbl[13] * z41 + tbl[15] * p4;
    const float SP3a = tbl[16] + tbl[18] * z40 + tbl[20] * z41 + tbl[22] * p4;
    const float SP3b = tbl[17] + tbl[19] * z40 + tbl[21] * z41 + tbl[23] * p4;
    const float p2 = z20 * z21;
    const float l1a  = tbl[24] + tbl[26] * z20 + tbl[28] * z21 + tbl[30] * p2;
    const float l1b  = tbl[25] + tbl[27] * z20 + tbl[29] * z21 + tbl[31] * p2;
    const float SP1a = tbl[32] + tbl[34] * z20 + tbl[36] * z21 + tbl[38] * p2;
    const float SP1b = tbl[33] + tbl[35] * z20 + tbl[37] * z21 + tbl[39] * p2;
    const float mu2  = tbl[40] + tbl[42] * z30 + tbl[44] * z31 + tbl[46] * p3;
    const float p1 = z10 * z11;
    const float mu1  = tbl[41] + tbl[43] * z10 + tbl[45] * z11 + tbl[47] * p1;

    lz += (SP1a - l1a * z10) + (SP1b - l1b * z11)
        + (sp_f(l20) - l20 * z20) + (sp_f(l21) - l21 * z21)
        + (SP3a - l3a * z30) + (SP3b - l3b * z31)
        - (L40 * z40 + L41 * z41);
    const float d1 = Y1 - mu1, d2 = Y2 - mu2;
    ly += d1 * d1 + d2 * d2;  // *2 applied in the reduce kernel
}

// ------------- kernel B: main, 2 samples/thread, NO atomics, no prologue -------------
__global__ __launch_bounds__(NT, 4) void wake_main(
    const float* __restrict__ y1, const float* __restrict__ y2,
    const float* __restrict__ n1, const float* __restrict__ n2,
    const float* __restrict__ n3, const float* __restrict__ n4,
    const float* __restrict__ i0w1, const float* __restrict__ i0b1,
    const float* __restrict__ i0w2, const float* __restrict__ i0b2,
    const float* __restrict__ i1w1, const float* __restrict__ i1b1,
    const float* __restrict__ i1w2, const float* __restrict__ i1b2,
    const float* __restrict__ i2w1, const float* __restrict__ i2b1,
    const float* __restrict__ i2w2, const float* __restrict__ i2b2,
    const float* __restrict__ g3w1, const float* __restrict__ g3b1,
    const float* __restrict__ g3w2, const float* __restrict__ g3b2,
    const float* __restrict__ g0w,
    const float* __restrict__ tbl,
    float2* __restrict__ partials)
{
    const int tid = threadIdx.x;
    const int g = blockIdx.x * NT + tid;

    // per-thread data: 80 B in 6 wide coalesced loads, issued up front
    const float2 Y1v = reinterpret_cast<const float2*>(y1)[g];
    const float2 Y2v = reinterpret_cast<const float2*>(y2)[g];
    const float4 N1v = reinterpret_cast<const float4*>(n1)[g];
    const float4 N2v = reinterpret_cast<const float4*>(n2)[g];
    const float4 N3v = reinterpret_cast<const float4*>(n3)[g];
    const float4 N4v = reinterpret_cast<const float4*>(n4)[g];

    const float L40 = g0w[0], L41 = g0w[1];

    float lz = 0.0f, ly = 0.0f;
    sample_body(Y1v.x, Y2v.x, N1v.x, N1v.y, N2v.x, N2v.y,
                N3v.x, N3v.y, N4v.x, N4v.y,
                i0w1, i0b1, i0w2, i0b2, i1w1, i1b1, i1w2, i1b2,
                i2w1, i2b1, i2w2, i2b2, g3w1, g3b1, g3w2, g3b2,
                L40, L41, tbl, lz, ly);
    sample_body(Y1v.y, Y2v.y, N1v.z, N1v.w, N2v.z, N2v.w,
                N3v.z, N3v.w, N4v.z, N4v.w,
                i0w1, i0b1, i0w2, i0b2, i1w1, i1b1, i1w2, i1b2,
                i2w1, i2b1, i2w2, i2b2, g3w1, g3b1, g3w2, g3b2,
                L40, L41, tbl, lz, ly);

    // block reduction -> one float2 partial per block (plain store)
    #pragma unroll
    for (int off = 32; off > 0; off >>= 1) {
        lz += __shfl_down(lz, off);
        ly += __shfl_down(ly, off);
    }
    __shared__ float2 wsum[NT / 64];
    const int lane = tid & 63, wid = tid >> 6;
    if (lane == 0) wsum[wid] = make_float2(lz, ly);
    __syncthreads();
    if (tid == 0) {
        float a = 0.0f, b = 0.0f;
        #pragma unroll
        for (int w = 0; w < NT / 64; ++w) { a += wsum[w].x; b += wsum[w].y; }
        partials[blockIdx.x] = make_float2(a, b);
    }
}

// ---------------- kernel C: final reduce ----------------
__global__ __launch_bounds__(256) void wake_reduce(
    const float2* __restrict__ partials, const float* __restrict__ g0w,
    float* __restrict__ out)
{
    const int tid = threadIdx.x;
    float lz = 0.0f, ly = 0.0f;
    #pragma unroll
    for (int i = 0; i < NBLK / 256; ++i) {
        float2 p = partials[tid + i * 256];
        lz += p.x; ly += p.y;
    }
    #pragma unroll
    for (int off = 32; off > 0; off >>= 1) {
        lz += __shfl_down(lz, off);
        ly += __shfl_down(ly, off);
    }
    __shared__ float2 wsum[4];
    const int lane = tid & 63, wid = tid >> 6;
    if (lane == 0) wsum[wid] = make_float2(lz, ly);
    __syncthreads();
    if (tid == 0) {
        float a = 0.0f, b = 0.0f;
        #pragma unroll
        for (int w = 0; w < 4; ++w) { a += wsum[w].x; b += wsum[w].y; }
        const float l40 = g0w[0], l41 = g0w[1];
        const float c4 = fmaxf(l40, 0.0f) + log1pf(expf(-fabsf(l40)))
                       + fmaxf(l41, 0.0f) + log1pf(expf(-fabsf(l41)));
        const float inv = 1.0f / 1048576.0f;
        const float loss_z = a * inv + c4;
        const float loss_y = 2.0f * b * inv + 0.4515827052894548f;
        out[0] = loss_z + loss_y;
        out[1] = loss_z;
        out[2] = loss_y;
    }
}

extern "C" void kernel_launch(void* const* d_in, const int* in_sizes, int n_in,
                              void* d_out, int out_size, void* d_ws, size_t ws_size,
                              hipStream_t stream) {
    const float* p[43];
    for (int i = 0; i < 43; ++i) p[i] = (const float*)d_in[i];
    float2* partials = (float2*)d_ws;
    float* tbl = (float*)((char*)d_ws + TBL_OFF);

    // binary-input MLP weights: inf3=18..21, g1=22..25, g2=26..29, g4=34..37, g5=38..41
    make_tables<<<1, 64, 0, stream>>>(
        p[18], p[19], p[20], p[21],
        p[22], p[23], p[24], p[25],
        p[26], p[27], p[28], p[29],
        p[34], p[35], p[36], p[37],
        p[38], p[39], p[40], p[41],
        tbl);
    wake_main<<<NBLK, NT, 0, stream>>>(
        p[0], p[1], p[2], p[3], p[4], p[5],
        p[6], p[7], p[8], p[9],
        p[10], p[11], p[12], p[13],
        p[14], p[15], p[16], p[17],
        p[30], p[31], p[32], p[33],
        p[42], tbl, partials);
    wake_reduce<<<1, 256, 0, stream>>>(partials, p[42], (float*)d_out);
}

// Round 7
// 25.170 us; speedup vs baseline: 4.3472x; 1.2377x over previous
//
#include <hip/hip_runtime.h>
#include <math.h>

#define NBLK 4096
#define NT 256
// NBLK * NT * 1 sample/thread = 1048576 = B exactly.
#define TBL_OFF (NBLK * 8)  // coef table after float2 partials[NBLK]

typedef float f32x2 __attribute__((ext_vector_type(2)));

__device__ __forceinline__ f32x2 relu2(f32x2 v) {
    f32x2 z = {0.0f, 0.0f};
    return __builtin_elementwise_max(v, z);
}
__device__ __forceinline__ float zsel(float s, float n) {
    // (sigmoid(s) > n)  <=>  (1-n) > n*exp(-s)
    float e = __expf(-s);
    return (1.0f - n > n * e) ? 1.0f : 0.0f;
}
__device__ __forceinline__ float sp_f(float l) {  // softplus
    return fmaxf(l, 0.0f) + __logf(1.0f + __expf(-fabsf(l)));
}

// ---------------- kernel A: build bilinear coefficient tables ----------------
// tbl[(pair*4+t)*2+e]: P0=(sig40,sig41)[z3] P1=(l30,l31)[z4] P2=(SP30,SP31)[z4]
// P3=(l10,l11)[z2] P4=(SP10,SP11)[z2] P5=(muy2[z3], muy1[z1])
__global__ __launch_bounds__(64) void make_tables(
    const float* __restrict__ i3w1, const float* __restrict__ i3b1,
    const float* __restrict__ i3w2, const float* __restrict__ i3b2,
    const float* __restrict__ g1w1, const float* __restrict__ g1b1,
    const float* __restrict__ g1w2, const float* __restrict__ g1b2,
    const float* __restrict__ g2w1, const float* __restrict__ g2b1,
    const float* __restrict__ g2w2, const float* __restrict__ g2b2,
    const float* __restrict__ g4w1, const float* __restrict__ g4b1,
    const float* __restrict__ g4w2, const float* __restrict__ g4b2,
    const float* __restrict__ g5w1, const float* __restrict__ g5b1,
    const float* __restrict__ g5w2, const float* __restrict__ g5b2,
    float* __restrict__ tbl)
{
    __shared__ float lds_eval[5][4][2];
    const int tid = threadIdx.x;
    if (tid < 20) {
        const int m = tid >> 2, c = tid & 3;
        const float z0 = (float)(c & 1), z1f = (float)(c >> 1);
        const float *w1, *bb1, *w2, *bb2; int dout;
        switch (m) {
            case 0:  w1 = i3w1; bb1 = i3b1; w2 = i3w2; bb2 = i3b2; dout = 2; break;
            case 1:  w1 = g1w1; bb1 = g1b1; w2 = g1w2; bb2 = g1b2; dout = 2; break;
            case 2:  w1 = g2w1; bb1 = g2b1; w2 = g2w2; bb2 = g2b2; dout = 1; break;
            case 3:  w1 = g4w1; bb1 = g4b1; w2 = g4w2; bb2 = g4b2; dout = 2; break;
            default: w1 = g5w1; bb1 = g5b1; w2 = g5w2; bb2 = g5b2; dout = 1; break;
        }
        float o0 = bb2[0];
        float o1 = (dout == 2) ? bb2[1] : 0.0f;
        #pragma unroll
        for (int j = 0; j < 8; ++j) {
            float h = fmaxf(bb1[j] + z0 * w1[j] + z1f * w1[8 + j], 0.0f);
            o0 += h * w2[j * dout];
            if (dout == 2) o1 += h * w2[j * 2 + 1];
        }
        lds_eval[m][c][0] = o0;
        lds_eval[m][c][1] = o1;
    }
    __syncthreads();
    if (tid < 12) {
        const int pair = tid >> 1, elem = tid & 1;
        int m, k, tf;
        switch (tid) {
            case 0:  m = 0; k = 0; tf = 1; break;  // sig40
            case 1:  m = 0; k = 1; tf = 1; break;  // sig41
            case 2:  m = 1; k = 0; tf = 0; break;  // l30
            case 3:  m = 1; k = 1; tf = 0; break;  // l31
            case 4:  m = 1; k = 0; tf = 2; break;  // SP30
            case 5:  m = 1; k = 1; tf = 2; break;  // SP31
            case 6:  m = 3; k = 0; tf = 0; break;  // l10
            case 7:  m = 3; k = 1; tf = 0; break;  // l11
            case 8:  m = 3; k = 0; tf = 2; break;  // SP10
            case 9:  m = 3; k = 1; tf = 2; break;  // SP11
            case 10: m = 2; k = 0; tf = 0; break;  // muy2
            default: m = 4; k = 0; tf = 0; break;  // muy1
        }
        float f[4];
        #pragma unroll
        for (int c = 0; c < 4; ++c) {
            float x = lds_eval[m][c][k];
            if (tf == 1)      x = 1.0f / (1.0f + expf(-x));
            else if (tf == 2) x = fmaxf(x, 0.0f) + log1pf(expf(-fabsf(x)));
            f[c] = x;
        }
        tbl[(pair * 4 + 0) * 2 + elem] = f[0];
        tbl[(pair * 4 + 1) * 2 + elem] = f[1] - f[0];
        tbl[(pair * 4 + 2) * 2 + elem] = f[2] - f[0];
        tbl[(pair * 4 + 3) * 2 + elem] = f[3] - f[1] - f[2] + f[0];
    }
}

// Weight f32x2 from two ADJACENT SCALAR reads (stays uniform/SGPR — never
// pointer-cast the weight arrays to vector types: R2 bug, demotes to VMEM).
#define WPAIR(ptr, idx) (f32x2{(ptr)[idx], (ptr)[(idx) + 1]})

// ---------------- kernel B: main, 1 sample/thread, packed-pair math ----------------
__global__ __launch_bounds__(NT, 6) void wake_main(
    const float* __restrict__ y1, const float* __restrict__ y2,
    const float* __restrict__ n1, const float* __restrict__ n2,
    const float* __restrict__ n3, const float* __restrict__ n4,
    const float* __restrict__ i0w1, const float* __restrict__ i0b1,
    const float* __restrict__ i0w2, const float* __restrict__ i0b2,
    const float* __restrict__ i1w1, const float* __restrict__ i1b1,
    const float* __restrict__ i1w2, const float* __restrict__ i1b2,
    const float* __restrict__ i2w1, const float* __restrict__ i2b1,
    const float* __restrict__ i2w2, const float* __restrict__ i2b2,
    const float* __restrict__ g3w1, const float* __restrict__ g3b1,
    const float* __restrict__ g3w2, const float* __restrict__ g3b2,
    const float* __restrict__ g0w,
    const float* __restrict__ tbl,
    float2* __restrict__ partials)
{
    const int tid = threadIdx.x;
    const int g = blockIdx.x * NT + tid;

    // per-thread data: 40 B in 6 coalesced loads, issued up front
    const float Y1 = y1[g];
    const float Y2 = y2[g];
    const float2 N1 = reinterpret_cast<const float2*>(n1)[g];
    const float2 N2 = reinterpret_cast<const float2*>(n2)[g];
    const float2 N3 = reinterpret_cast<const float2*>(n3)[g];
    const float2 N4 = reinterpret_cast<const float2*>(n4)[g];

    // inf0([y1,y2]) -> z1   (hidden j-pairs and the 2 outputs packed)
    f32x2 acc0 = WPAIR(i0b2, 0);
    #pragma unroll
    for (int jp = 0; jp < 4; ++jp) {
        const int j = 2 * jp;
        f32x2 h = relu2(WPAIR(i0b1, j) + Y1 * WPAIR(i0w1, j) + Y2 * WPAIR(i0w1, 8 + j));
        acc0 += h.x * WPAIR(i0w2, 2 * j) + h.y * WPAIR(i0w2, 2 * j + 2);
    }
    const float z10 = zsel(acc0.x, N1.x);
    const float z11 = zsel(acc0.y, N1.y);

    // inf1([y2,z1]) -> z2
    f32x2 acc1 = WPAIR(i1b2, 0);
    #pragma unroll
    for (int jp = 0; jp < 4; ++jp) {
        const int j = 2 * jp;
        f32x2 h = relu2(WPAIR(i1b1, j) + Y2 * WPAIR(i1w1, j)
                        + z10 * WPAIR(i1w1, 8 + j) + z11 * WPAIR(i1w1, 16 + j));
        acc1 += h.x * WPAIR(i1w2, 2 * j) + h.y * WPAIR(i1w2, 2 * j + 2);
    }
    const float z20 = zsel(acc1.x, N2.x);
    const float z21 = zsel(acc1.y, N2.y);

    // inf2(y2) -> z3
    f32x2 acc2 = WPAIR(i2b2, 0);
    #pragma unroll
    for (int jp = 0; jp < 4; ++jp) {
        const int j = 2 * jp;
        f32x2 h = relu2(WPAIR(i2b1, j) + Y2 * WPAIR(i2w1, j));
        acc2 += h.x * WPAIR(i2w2, 2 * j) + h.y * WPAIR(i2w2, 2 * j + 2);
    }
    const float z30 = zsel(acc2.x, N3.x);
    const float z31 = zsel(acc2.y, N3.y);

    // z4 via tabulated sigmoid over z3 corners (packed pair)
    const float p3 = z30 * z31;
    const f32x2 sg = WPAIR(tbl, 0) + z30 * WPAIR(tbl, 2) + z31 * WPAIR(tbl, 4) + p3 * WPAIR(tbl, 6);
    const float z40 = (sg.x > N4.x) ? 1.0f : 0.0f;
    const float z41 = (sg.y > N4.y) ? 1.0f : 0.0f;
    const float p4 = z40 * z41;

    // g3(y2) -> l2 (continuous-input MLP)
    f32x2 l2 = WPAIR(g3b2, 0);
    #pragma unroll
    for (int jp = 0; jp < 4; ++jp) {
        const int j = 2 * jp;
        f32x2 h = relu2(WPAIR(g3b1, j) + Y2 * WPAIR(g3w1, j));
        l2 += h.x * WPAIR(g3w2, 2 * j) + h.y * WPAIR(g3w2, 2 * j + 2);
    }

    // table losses, all pairs packed
    const f32x2 l3  = WPAIR(tbl, 8)  + z40 * WPAIR(tbl, 10) + z41 * WPAIR(tbl, 12) + p4 * WPAIR(tbl, 14);
    const f32x2 SP3 = WPAIR(tbl, 16) + z40 * WPAIR(tbl, 18) + z41 * WPAIR(tbl, 20) + p4 * WPAIR(tbl, 22);
    const float p2 = z20 * z21;
    const f32x2 l1  = WPAIR(tbl, 24) + z20 * WPAIR(tbl, 26) + z21 * WPAIR(tbl, 28) + p2 * WPAIR(tbl, 30);
    const f32x2 SP1 = WPAIR(tbl, 32) + z20 * WPAIR(tbl, 34) + z21 * WPAIR(tbl, 36) + p2 * WPAIR(tbl, 38);
    const float p1 = z10 * z11;
    const f32x2 zA = {z30, z10}, zB = {z31, z11}, zP = {p3, p1};
    const f32x2 mu = WPAIR(tbl, 40) + zA * WPAIR(tbl, 42) + zB * WPAIR(tbl, 44) + zP * WPAIR(tbl, 46);  // (muy2, muy1)
    const float L40 = g0w[0], L41 = g0w[1];

    const f32x2 z1v = {z10, z11}, z2v = {z20, z21}, z3v = {z30, z31};
    f32x2 sp2 = {sp_f(l2.x), sp_f(l2.y)};
    f32x2 bsum = (SP1 - l1 * z1v) + (SP3 - l3 * z3v) + (sp2 - l2 * z2v);
    float lz = bsum.x + bsum.y - (L40 * z40 + L41 * z41);
    const f32x2 d = {Y2 - mu.x, Y1 - mu.y};
    const f32x2 dd = d * d;
    float ly = dd.x + dd.y;  // *2 applied in the reduce kernel

    // block reduction -> one float2 partial per block (plain store)
    #pragma unroll
    for (int off = 32; off > 0; off >>= 1) {
        lz += __shfl_down(lz, off);
        ly += __shfl_down(ly, off);
    }
    __shared__ float2 wsum[NT / 64];
    const int lane = tid & 63, wid = tid >> 6;
    if (lane == 0) wsum[wid] = make_float2(lz, ly);
    __syncthreads();
    if (tid == 0) {
        float a = 0.0f, b = 0.0f;
        #pragma unroll
        for (int w = 0; w < NT / 64; ++w) { a += wsum[w].x; b += wsum[w].y; }
        partials[blockIdx.x] = make_float2(a, b);
    }
}

// ---------------- kernel C: final reduce ----------------
__global__ __launch_bounds__(256) void wake_reduce(
    const float2* __restrict__ partials, const float* __restrict__ g0w,
    float* __restrict__ out)
{
    const int tid = threadIdx.x;
    float lz = 0.0f, ly = 0.0f;
    #pragma unroll
    for (int i = 0; i < NBLK / 256; ++i) {
        float2 p = partials[tid + i * 256];
        lz += p.x; ly += p.y;
    }
    #pragma unroll
    for (int off = 32; off > 0; off >>= 1) {
        lz += __shfl_down(lz, off);
        ly += __shfl_down(ly, off);
    }
    __shared__ float2 wsum[4];
    const int lane = tid & 63, wid = tid >> 6;
    if (lane == 0) wsum[wid] = make_float2(lz, ly);
    __syncthreads();
    if (tid == 0) {
        float a = 0.0f, b = 0.0f;
        #pragma unroll
        for (int w = 0; w < 4; ++w) { a += wsum[w].x; b += wsum[w].y; }
        const float l40 = g0w[0], l41 = g0w[1];
        const float c4 = fmaxf(l40, 0.0f) + log1pf(expf(-fabsf(l40)))
                       + fmaxf(l41, 0.0f) + log1pf(expf(-fabsf(l41)));
        const float inv = 1.0f / 1048576.0f;
        const float loss_z = a * inv + c4;
        const float loss_y = 2.0f * b * inv + 0.4515827052894548f;
        out[0] = loss_z + loss_y;
        out[1] = loss_z;
        out[2] = loss_y;
    }
}

extern "C" void kernel_launch(void* const* d_in, const int* in_sizes, int n_in,
                              void* d_out, int out_size, void* d_ws, size_t ws_size,
                              hipStream_t stream) {
    const float* p[43];
    for (int i = 0; i < 43; ++i) p[i] = (const float*)d_in[i];
    float2* partials = (float2*)d_ws;
    float* tbl = (float*)((char*)d_ws + TBL_OFF);

    // binary-input MLP weights: inf3=18..21, g1=22..25, g2=26..29, g4=34..37, g5=38..41
    make_tables<<<1, 64, 0, stream>>>(
        p[18], p[19], p[20], p[21],
        p[22], p[23], p[24], p[25],
        p[26], p[27], p[28], p[29],
        p[34], p[35], p[36], p[37],
        p[38], p[39], p[40], p[41],
        tbl);
    wake_main<<<NBLK, NT, 0, stream>>>(
        p[0], p[1], p[2], p[3], p[4], p[5],
        p[6], p[7], p[8], p[9],
        p[10], p[11], p[12], p[13],
        p[14], p[15], p[16], p[17],
        p[30], p[31], p[32], p[33],
        p[42], tbl, partials);
    wake_reduce<<<1, 256, 0, stream>>>(partials, p[42], (float*)d_out);
}